// Round 5
// baseline (2353.955 us; speedup 1.0000x reference)
//
#include <hip/hip_runtime.h>
#include <cstdint>
#include <cstddef>

// Problem constants
#define B_   32
#define N_   1024
#define H_   512
#define E_   1024
#define S_   128
#define NW_  2176            // 2E + S
#define R_   (B_ * N_)       // 32768 rows total

static __device__ __forceinline__ float silu_f(float x) {
    return x / (1.0f + expf(-x));
}

// ---------------------------------------------------------------------------
// Kernel 1: per-row scale factor  s[r] = g / max(||x_r|| * H^-0.5, eps)
// One wave (64 lanes) per row; block of 256 = 4 rows. Full problem, once.
// ---------------------------------------------------------------------------
__global__ __launch_bounds__(256) void scale_kernel(
    const float* __restrict__ x, const float* __restrict__ g,
    float* __restrict__ s)
{
    int row  = blockIdx.x * 4 + (threadIdx.x >> 6);
    int lane = threadIdx.x & 63;
    const float4* xr = (const float4*)(x + (size_t)row * H_);
    float4 a = xr[lane];        // H_=512 -> 128 float4 per row
    float4 b = xr[lane + 64];
    float acc = a.x*a.x + a.y*a.y + a.z*a.z + a.w*a.w
              + b.x*b.x + b.y*b.y + b.z*b.z + b.w*b.w;
    #pragma unroll
    for (int off = 1; off < 64; off <<= 1)
        acc += __shfl_xor(acc, off);
    if (lane == 0) {
        float norm = sqrtf(acc) * 0.044194173824159216f;   // * 512^-0.5
        s[row] = g[0] / fmaxf(norm, 1e-5f);
    }
}

// ---------------------------------------------------------------------------
// Kernel 2: RoPE trig tables in fp64 so the fp32 result is correctly rounded.
// sinusoid = fp32(n) * fp32(10000^(i/64)); sin/cos of exactly that fp32 value.
// ---------------------------------------------------------------------------
__global__ __launch_bounds__(256) void trig_kernel(
    float* __restrict__ sin_t, float* __restrict__ cos_t)
{
    int idx = blockIdx.x * 256 + threadIdx.x;   // 0 .. N_*64-1
    int n = idx >> 6;
    int i = idx & 63;
    double invf_d = pow(10000.0, (double)i * (1.0 / 64.0));
    float  invf   = (float)invf_d;              // correctly-rounded fp32 inv_freq
    float  arg    = (float)n * invf;            // fp32 product, same as reference
    sin_t[idx] = (float)sin((double)arg);
    cos_t[idx] = (float)cos((double)arg);
}

// ---------------------------------------------------------------------------
// Kernel 3: GEMM1  silu(xn @ Wuv + buv), xn = x * s[row] applied on load.
// Operates on a CHUNK of rows (pointers pre-offset). 128x128 tile, BK=8,
// 256 threads, 8x8 microtile, register prefetch of the next K-slab.
// ---------------------------------------------------------------------------
__global__ __launch_bounds__(256) void gemm1_kernel(
    const float* __restrict__ x, const float* __restrict__ s,
    const float* __restrict__ Wuv, const float* __restrict__ buv,
    float* __restrict__ u, float* __restrict__ v, float* __restrict__ qb)
{
    __shared__ float As[8][128];
    __shared__ float Bs[8][128];
    const int tid = threadIdx.x;
    const int bm = blockIdx.x, bn = blockIdx.y;
    const int tx = tid & 15, ty = tid >> 4;
    const int arow = tid >> 1, ak = (tid & 1) * 4;
    const int brow = tid >> 5, bcol = (tid & 31) * 4;
    const float* Ap = x + (size_t)(bm * 128 + arow) * H_ + ak;
    const float  srow = s[bm * 128 + arow];
    const float* Bp = Wuv + (size_t)brow * NW_ + bn * 128 + bcol;

    float acc[8][8];
    #pragma unroll
    for (int i = 0; i < 8; i++)
        #pragma unroll
        for (int j = 0; j < 8; j++) acc[i][j] = 0.0f;

    float4 a4 = *(const float4*)(Ap);
    float4 b4 = *(const float4*)(Bp);
    for (int kt = 0; kt < H_; kt += 8) {
        As[ak + 0][arow] = a4.x * srow;
        As[ak + 1][arow] = a4.y * srow;
        As[ak + 2][arow] = a4.z * srow;
        As[ak + 3][arow] = a4.w * srow;
        *(float4*)&Bs[brow][bcol] = b4;
        __syncthreads();
        const int ktn = (kt + 8 < H_) ? kt + 8 : kt;   // clamped prefetch
        float4 a4n = *(const float4*)(Ap + ktn);
        float4 b4n = *(const float4*)(Bp + (size_t)ktn * NW_);
        #pragma unroll
        for (int kk = 0; kk < 8; kk++) {
            float a[8], b[8];
            *(float4*)&a[0] = *(const float4*)&As[kk][ty * 8];
            *(float4*)&a[4] = *(const float4*)&As[kk][ty * 8 + 4];
            *(float4*)&b[0] = *(const float4*)&Bs[kk][tx * 8];
            *(float4*)&b[4] = *(const float4*)&Bs[kk][tx * 8 + 4];
            #pragma unroll
            for (int i = 0; i < 8; i++)
                #pragma unroll
                for (int j = 0; j < 8; j++)
                    acc[i][j] += a[i] * b[j];
        }
        __syncthreads();
        a4 = a4n; b4 = b4n;
    }

    const int row0 = bm * 128 + ty * 8;
    const int col0 = bn * 128 + tx * 8;
    #pragma unroll
    for (int i = 0; i < 8; i++) {
        int row = row0 + i;
        #pragma unroll
        for (int j = 0; j < 8; j++) {
            int col = col0 + j;
            float r = silu_f(acc[i][j] + buv[col]);
            if (col < E_)            u[(size_t)row * E_ + col] = r;
            else if (col < 2 * E_)   v[(size_t)row * E_ + (col - E_)] = r;
            else                     qb[(size_t)row * S_ + (col - 2 * E_)] = r;
        }
    }
}

// ---------------------------------------------------------------------------
// Kernel 4: gamma/beta affine + RoPE on a chunk. base lives in qb; q written
// in place, k written to kb. One wave per row; lane i handles dims i, i+64.
// Chunk starts at a batch boundary so (local row & 1023) == position n.
// ---------------------------------------------------------------------------
__global__ __launch_bounds__(256) void rope_kernel(
    float* __restrict__ qb, float* __restrict__ kb,
    const float* __restrict__ gamma, const float* __restrict__ beta,
    const float* __restrict__ sin_t, const float* __restrict__ cos_t)
{
    int row = blockIdx.x * 4 + (threadIdx.x >> 6);
    int i   = threadIdx.x & 63;
    int n   = row & (N_ - 1);
    size_t base = (size_t)row * S_;
    float b1 = qb[base + i];
    float b2 = qb[base + i + 64];
    float sn = sin_t[n * 64 + i];
    float cs = cos_t[n * 64 + i];
    // q: gamma/beta row 0
    float t1 = b1 * gamma[i]      + beta[i];
    float t2 = b2 * gamma[i + 64] + beta[i + 64];
    qb[base + i]      = t1 * cs - t2 * sn;
    qb[base + i + 64] = t2 * cs + t1 * sn;
    // k: gamma/beta row 1
    t1 = b1 * gamma[128 + i]      + beta[128 + i];
    t2 = b2 * gamma[128 + i + 64] + beta[128 + i + 64];
    kb[base + i]      = t1 * cs - t2 * sn;
    kb[base + i + 64] = t2 * cs + t1 * sn;
}

// ---------------------------------------------------------------------------
// Kernel 5: batched NT GEMM  A[b] = relu(q kT / sqrt(S))^2  (chunk batches)
// ---------------------------------------------------------------------------
__global__ __launch_bounds__(256) void qk_kernel(
    const float* __restrict__ q, const float* __restrict__ k,
    float* __restrict__ A)
{
    __shared__ float Qs[8][128];
    __shared__ float Ks[8][128];
    const int tid = threadIdx.x;
    const int bm = blockIdx.x, bn = blockIdx.y, b = blockIdx.z;
    const int tx = tid & 15, ty = tid >> 4;
    const int arow = tid >> 1, ak = (tid & 1) * 4;
    const float* Qp = q + (size_t)b * N_ * S_ + (size_t)(bm * 128 + arow) * S_ + ak;
    const float* Kp = k + (size_t)b * N_ * S_ + (size_t)(bn * 128 + arow) * S_ + ak;

    float acc[8][8];
    #pragma unroll
    for (int i = 0; i < 8; i++)
        #pragma unroll
        for (int j = 0; j < 8; j++) acc[i][j] = 0.0f;

    float4 a4 = *(const float4*)(Qp);
    float4 b4 = *(const float4*)(Kp);
    for (int kt = 0; kt < S_; kt += 8) {
        Qs[ak + 0][arow] = a4.x; Qs[ak + 1][arow] = a4.y;
        Qs[ak + 2][arow] = a4.z; Qs[ak + 3][arow] = a4.w;
        Ks[ak + 0][arow] = b4.x; Ks[ak + 1][arow] = b4.y;
        Ks[ak + 2][arow] = b4.z; Ks[ak + 3][arow] = b4.w;
        __syncthreads();
        const int ktn = (kt + 8 < S_) ? kt + 8 : kt;
        float4 a4n = *(const float4*)(Qp + ktn);
        float4 b4n = *(const float4*)(Kp + ktn);
        #pragma unroll
        for (int kk = 0; kk < 8; kk++) {
            float a[8], bb[8];
            *(float4*)&a[0]  = *(const float4*)&Qs[kk][ty * 8];
            *(float4*)&a[4]  = *(const float4*)&Qs[kk][ty * 8 + 4];
            *(float4*)&bb[0] = *(const float4*)&Ks[kk][tx * 8];
            *(float4*)&bb[4] = *(const float4*)&Ks[kk][tx * 8 + 4];
            #pragma unroll
            for (int i = 0; i < 8; i++)
                #pragma unroll
                for (int j = 0; j < 8; j++)
                    acc[i][j] += a[i] * bb[j];
        }
        __syncthreads();
        a4 = a4n; b4 = b4n;
    }

    const int row0 = bm * 128 + ty * 8;
    const int col0 = bn * 128 + tx * 8;
    float* Ab = A + (size_t)b * N_ * N_;
    #pragma unroll
    for (int i = 0; i < 8; i++)
        #pragma unroll
        for (int j = 0; j < 8; j++) {
            float t = acc[i][j] / 11.313708498984761f;  // / sqrt(128)
            t = fmaxf(t, 0.0f);
            Ab[(size_t)(row0 + i) * N_ + (col0 + j)] = t * t;
        }
}

// ---------------------------------------------------------------------------
// Kernel 6: batched NN GEMM  y = u .* (A @ v)  — stored back INTO u (each
// output element reads exactly its own u element, so aliasing is safe).
// ---------------------------------------------------------------------------
__global__ __launch_bounds__(256) void av_kernel(
    const float* __restrict__ A, const float* __restrict__ v,
    float* __restrict__ uy)
{
    __shared__ float As[8][128];
    __shared__ float Bs[8][128];
    const int tid = threadIdx.x;
    const int bm = blockIdx.x, bn = blockIdx.y, b = blockIdx.z;
    const int tx = tid & 15, ty = tid >> 4;
    const int arow = tid >> 1, ak = (tid & 1) * 4;
    const int brow = tid >> 5, bcol = (tid & 31) * 4;
    const float* Ap = A + (size_t)b * N_ * N_ + (size_t)(bm * 128 + arow) * N_ + ak;
    const float* Bp = v + (size_t)b * N_ * E_ + (size_t)brow * E_ + bn * 128 + bcol;

    float acc[8][8];
    #pragma unroll
    for (int i = 0; i < 8; i++)
        #pragma unroll
        for (int j = 0; j < 8; j++) acc[i][j] = 0.0f;

    float4 a4 = *(const float4*)(Ap);
    float4 b4 = *(const float4*)(Bp);
    for (int kt = 0; kt < N_; kt += 8) {
        As[ak + 0][arow] = a4.x; As[ak + 1][arow] = a4.y;
        As[ak + 2][arow] = a4.z; As[ak + 3][arow] = a4.w;
        *(float4*)&Bs[brow][bcol] = b4;
        __syncthreads();
        const int ktn = (kt + 8 < N_) ? kt + 8 : kt;
        float4 a4n = *(const float4*)(Ap + ktn);
        float4 b4n = *(const float4*)(Bp + (size_t)ktn * E_);
        #pragma unroll
        for (int kk = 0; kk < 8; kk++) {
            float a[8], bb[8];
            *(float4*)&a[0]  = *(const float4*)&As[kk][ty * 8];
            *(float4*)&a[4]  = *(const float4*)&As[kk][ty * 8 + 4];
            *(float4*)&bb[0] = *(const float4*)&Bs[kk][tx * 8];
            *(float4*)&bb[4] = *(const float4*)&Bs[kk][tx * 8 + 4];
            #pragma unroll
            for (int i = 0; i < 8; i++)
                #pragma unroll
                for (int j = 0; j < 8; j++)
                    acc[i][j] += a[i] * bb[j];
        }
        __syncthreads();
        a4 = a4n; b4 = b4n;
    }

    const int row0 = bm * 128 + ty * 8;
    const int col0 = bn * 128 + tx * 8;
    #pragma unroll
    for (int i = 0; i < 8; i++) {
        size_t grow = (size_t)b * N_ + row0 + i;
        #pragma unroll
        for (int j = 0; j < 8; j++) {
            size_t idx = grow * E_ + (col0 + j);
            uy[idx] = uy[idx] * acc[i][j];
        }
    }
}

// ---------------------------------------------------------------------------
// Kernel 7: final NN GEMM  out = y @ Wo + bo + x  (chunk rows, K=1024, N=512)
// ---------------------------------------------------------------------------
__global__ __launch_bounds__(256) void final_kernel(
    const float* __restrict__ y, const float* __restrict__ Wo,
    const float* __restrict__ bo, const float* __restrict__ x,
    float* __restrict__ out)
{
    __shared__ float As[8][128];
    __shared__ float Bs[8][128];
    const int tid = threadIdx.x;
    const int bm = blockIdx.x, bn = blockIdx.y;
    const int tx = tid & 15, ty = tid >> 4;
    const int arow = tid >> 1, ak = (tid & 1) * 4;
    const int brow = tid >> 5, bcol = (tid & 31) * 4;
    const float* Ap = y + (size_t)(bm * 128 + arow) * E_ + ak;
    const float* Bp = Wo + (size_t)brow * H_ + bn * 128 + bcol;

    float acc[8][8];
    #pragma unroll
    for (int i = 0; i < 8; i++)
        #pragma unroll
        for (int j = 0; j < 8; j++) acc[i][j] = 0.0f;

    float4 a4 = *(const float4*)(Ap);
    float4 b4 = *(const float4*)(Bp);
    for (int kt = 0; kt < E_; kt += 8) {
        As[ak + 0][arow] = a4.x; As[ak + 1][arow] = a4.y;
        As[ak + 2][arow] = a4.z; As[ak + 3][arow] = a4.w;
        *(float4*)&Bs[brow][bcol] = b4;
        __syncthreads();
        const int ktn = (kt + 8 < E_) ? kt + 8 : kt;
        float4 a4n = *(const float4*)(Ap + ktn);
        float4 b4n = *(const float4*)(Bp + (size_t)ktn * H_);
        #pragma unroll
        for (int kk = 0; kk < 8; kk++) {
            float a[8], bb[8];
            *(float4*)&a[0]  = *(const float4*)&As[kk][ty * 8];
            *(float4*)&a[4]  = *(const float4*)&As[kk][ty * 8 + 4];
            *(float4*)&bb[0] = *(const float4*)&Bs[kk][tx * 8];
            *(float4*)&bb[4] = *(const float4*)&Bs[kk][tx * 8 + 4];
            #pragma unroll
            for (int i = 0; i < 8; i++)
                #pragma unroll
                for (int j = 0; j < 8; j++)
                    acc[i][j] += a[i] * bb[j];
        }
        __syncthreads();
        a4 = a4n; b4 = b4n;
    }

    const int row0 = bm * 128 + ty * 8;
    const int col0 = bn * 128 + tx * 8;
    #pragma unroll
    for (int i = 0; i < 8; i++) {
        int row = row0 + i;
        #pragma unroll
        for (int j = 0; j < 8; j++) {
            int col = col0 + j;
            out[(size_t)row * H_ + col] =
                acc[i][j] + bo[col] + x[(size_t)row * H_ + col];
        }
    }
}

// ---------------------------------------------------------------------------
extern "C" void kernel_launch(void* const* d_in, const int* in_sizes, int n_in,
                              void* d_out, int out_size, void* d_ws, size_t ws_size,
                              hipStream_t stream)
{
    const float* x     = (const float*)d_in[0];
    const float* Wuv   = (const float*)d_in[1];
    const float* buv   = (const float*)d_in[2];
    const float* gamma = (const float*)d_in[3];
    const float* beta  = (const float*)d_in[4];
    const float* Wo    = (const float*)d_in[5];
    const float* bo    = (const float*)d_in[6];
    const float* g     = (const float*)d_in[7];
    float* out = (float*)d_out;

    // --- ws_size-adaptive batch chunking -----------------------------------
    // fixed: s_buf (R_) + sin/cos tables (2*65536) floats
    // per-chunk (c batches): qb+kb (c*1024*256) + u+v (c*1024*2048)
    //                        + A (c*1024*1024)  = c * 3,407,872 floats
    const size_t fixedf = (size_t)R_ + 2 * 65536;
    int c = 16;                              // cap at 16 (209 MB) deliberately
    while (c > 1) {
        size_t need = (fixedf + (size_t)c * 3407872ull) * 4ull;
        if (need <= ws_size) break;
        c >>= 1;
    }
    const int Rc = c * N_;

    float* ws    = (float*)d_ws;
    float* s_buf = ws;
    float* sin_t = s_buf + R_;
    float* cos_t = sin_t + (size_t)N_ * 64;
    float* qb    = cos_t + (size_t)N_ * 64;
    float* kb    = qb + (size_t)Rc * S_;
    float* u_c   = kb + (size_t)Rc * S_;
    float* v_c   = u_c + (size_t)Rc * E_;
    float* A_c   = v_c + (size_t)Rc * E_;

    scale_kernel<<<R_ / 4, 256, 0, stream>>>(x, g, s_buf);
    trig_kernel<<<(N_ * 64) / 256, 256, 0, stream>>>(sin_t, cos_t);

    for (int b0 = 0; b0 < B_; b0 += c) {
        const size_t ro = (size_t)b0 * N_;   // starting row of this chunk
        gemm1_kernel<<<dim3(Rc / 128, NW_ / 128), 256, 0, stream>>>(
            x + ro * H_, s_buf + ro, Wuv, buv, u_c, v_c, qb);
        rope_kernel<<<Rc / 4, 256, 0, stream>>>(
            qb, kb, gamma, beta, sin_t, cos_t);
        qk_kernel<<<dim3(N_ / 128, N_ / 128, c), 256, 0, stream>>>(
            qb, kb, A_c);
        av_kernel<<<dim3(N_ / 128, N_ / 128, c), 256, 0, stream>>>(
            A_c, v_c, u_c);
        final_kernel<<<dim3(Rc / 128, H_ / 128), 256, 0, stream>>>(
            u_c, Wo, bo, x + ro * H_, out + ro * H_);
    }
}

// Round 6
// 1595.660 us; speedup vs baseline: 1.4752x; 1.4752x over previous
//
#include <hip/hip_runtime.h>
#include <cstdint>
#include <cstddef>

// Problem constants
#define B_   32
#define N_   1024
#define H_   512
#define E_   1024
#define S_   128
#define NW_  2176            // 2E + S
#define R_   (B_ * N_)       // 32768 rows total

typedef unsigned short u16;
typedef __attribute__((ext_vector_type(8))) short bf16x8;
typedef __attribute__((ext_vector_type(4))) float f32x4;

static __device__ __forceinline__ float silu_f(float x) {
    return x / (1.0f + expf(-x));
}
// bf16 round-to-nearest-even split helpers (inputs finite)
static __device__ __forceinline__ u16 f2bf(float f) {
    unsigned u = __float_as_uint(f);
    unsigned r = u + 0x7fffu + ((u >> 16) & 1u);
    return (u16)(r >> 16);
}
static __device__ __forceinline__ float b2f(u16 h) {
    return __uint_as_float(((unsigned)h) << 16);
}

// direct global->LDS 16B async copy (per-lane global src, linear LDS dest)
#define GLOAD_LDS16(SRC, DST)                                                  \
    __builtin_amdgcn_global_load_lds(                                          \
        (const __attribute__((address_space(1))) void*)(SRC),                  \
        (__attribute__((address_space(3))) void*)(DST), 16, 0, 0)

// ---------------------------------------------------------------------------
// Shared MFMA core: C[128x128] tile of A[rows][KP] x B^T[cols][KP] (both
// bf16 row-major with ld == KP, k-contiguous). LDS tiles are [128][64] bf16
// XOR-swizzled (byte ^= (row&7)<<4); global_load_lds writes linearly, so the
// SOURCE address is inverse-swizzled (rule #21: both-sides-or-neither).
// 4 waves, each computes a 64x64 quadrant as 4x4 16x16x32 fragments.
// ---------------------------------------------------------------------------
__device__ __forceinline__ void mm_tile_core(
    const u16* __restrict__ Atile, const u16* __restrict__ Btile,
    int KP, u16* As, u16* Bs, f32x4 acc[4][4])
{
    const int tid  = threadIdx.x;
    const int lane = tid & 63, wid = tid >> 6;
    const int wr = wid >> 1, wc = wid & 1;
    const int trow = tid >> 3;            // row within 32-row staging block
    const int p    = (tid & 7) * 16;      // physical byte offset within row

    for (int kt = 0; kt < KP; kt += 64) {
        #pragma unroll
        for (int s = 0; s < 4; s++) {
            const int row = s * 32 + trow;
            const int kb  = p ^ ((row & 7) << 4);   // inverse-swizzled source
            GLOAD_LDS16(Atile + (size_t)row * KP + kt + (kb >> 1),
                        (char*)As + s * 4096 + wid * 1024);
            GLOAD_LDS16(Btile + (size_t)row * KP + kt + (kb >> 1),
                        (char*)Bs + s * 4096 + wid * 1024);
        }
        __syncthreads();                  // drains vmcnt before barrier
        #pragma unroll
        for (int kk = 0; kk < 2; kk++) {
            const int kbyte = kk * 64 + (lane >> 4) * 16;
            bf16x8 af[4], bf[4];
            #pragma unroll
            for (int f = 0; f < 4; f++) {
                const int ra = wr * 64 + f * 16 + (lane & 15);
                af[f] = *(const bf16x8*)((const char*)As + ra * 128 +
                                         (kbyte ^ ((ra & 7) << 4)));
                const int rb = wc * 64 + f * 16 + (lane & 15);
                bf[f] = *(const bf16x8*)((const char*)Bs + rb * 128 +
                                         (kbyte ^ ((rb & 7) << 4)));
            }
            #pragma unroll
            for (int i = 0; i < 4; i++)
                #pragma unroll
                for (int j = 0; j < 4; j++)
                    acc[i][j] = __builtin_amdgcn_mfma_f32_16x16x32_bf16(
                        af[i], bf[j], acc[i][j], 0, 0, 0);
        }
        __syncthreads();
    }
}

// ---------------------------------------------------------------------------
// Kernel 1: per-row scale factor (unchanged, verified)
// ---------------------------------------------------------------------------
__global__ __launch_bounds__(256) void scale_kernel(
    const float* __restrict__ x, const float* __restrict__ g,
    float* __restrict__ s)
{
    int row  = blockIdx.x * 4 + (threadIdx.x >> 6);
    int lane = threadIdx.x & 63;
    const float4* xr = (const float4*)(x + (size_t)row * H_);
    float4 a = xr[lane];
    float4 b = xr[lane + 64];
    float acc = a.x*a.x + a.y*a.y + a.z*a.z + a.w*a.w
              + b.x*b.x + b.y*b.y + b.z*b.z + b.w*b.w;
    #pragma unroll
    for (int off = 1; off < 64; off <<= 1)
        acc += __shfl_xor(acc, off);
    if (lane == 0) {
        float norm = sqrtf(acc) * 0.044194173824159216f;
        s[row] = g[0] / fmaxf(norm, 1e-5f);
    }
}

// ---------------------------------------------------------------------------
// Kernel 2: RoPE trig tables in fp64 (unchanged, verified)
// ---------------------------------------------------------------------------
__global__ __launch_bounds__(256) void trig_kernel(
    float* __restrict__ sin_t, float* __restrict__ cos_t)
{
    int idx = blockIdx.x * 256 + threadIdx.x;
    int n = idx >> 6;
    int i = idx & 63;
    double invf_d = pow(10000.0, (double)i * (1.0 / 64.0));
    float  invf   = (float)invf_d;
    float  arg    = (float)n * invf;
    sin_t[idx] = (float)sin((double)arg);
    cos_t[idx] = (float)cos((double)arg);
}

// ---------------------------------------------------------------------------
// Conversion: xn' = split(x*s)  A-side layout [hi|hi|lo], K'=1536
// ---------------------------------------------------------------------------
__global__ __launch_bounds__(256) void xnp_kernel(
    const float* __restrict__ x, const float* __restrict__ s,
    u16* __restrict__ xnP)
{
    int idx = blockIdx.x * 256 + threadIdx.x;    // Rc*512 elements
    int r = idx >> 9, k = idx & 511;
    float v = x[(size_t)r * H_ + k] * s[r];
    u16 h = f2bf(v), l = f2bf(v - b2f(h));
    u16* xr = xnP + (size_t)r * 1536;
    xr[k] = h; xr[512 + k] = h; xr[1024 + k] = l;
}

// ---------------------------------------------------------------------------
// Conversion: WuvT' B-side layout [hi|lo|hi], [col 2176][K'=1536] (once)
// ---------------------------------------------------------------------------
__global__ __launch_bounds__(256) void wuvt_kernel(
    const float* __restrict__ Wuv, u16* __restrict__ WuvT)
{
    int k = blockIdx.x;                           // 0..511
    for (int c = threadIdx.x; c < NW_; c += 256) {
        float v = Wuv[(size_t)k * NW_ + c];
        u16 h = f2bf(v), l = f2bf(v - b2f(h));
        u16* wr = WuvT + (size_t)c * 1536;
        wr[k] = h; wr[512 + k] = l; wr[1024 + k] = h;
    }
}

// ---------------------------------------------------------------------------
// Conversion: WoT' B-side layout [hi|lo|hi], [col 512][K'=3072] (once)
// ---------------------------------------------------------------------------
__global__ __launch_bounds__(256) void wot_kernel(
    const float* __restrict__ Wo, u16* __restrict__ WoT)
{
    int k = blockIdx.x;                           // 0..1023
    for (int c = threadIdx.x; c < H_; c += 256) {
        float v = Wo[(size_t)k * H_ + c];
        u16 h = f2bf(v), l = f2bf(v - b2f(h));
        u16* wr = WoT + (size_t)c * 3072;
        wr[k] = h; wr[1024 + k] = l; wr[2048 + k] = h;
    }
}

// ---------------------------------------------------------------------------
// GEMM1 (MFMA): silu(xn@Wuv+buv) -> u fp32 | v split-bf16 (B-side, per-batch
// [e][K'=3072] at k'=m,1024+m,2048+m = hi,lo,hi) | qb fp32
// ---------------------------------------------------------------------------
__global__ __launch_bounds__(256) void gemm1_mfma(
    const u16* __restrict__ xnP, const u16* __restrict__ WuvT,
    const float* __restrict__ buv,
    float* __restrict__ u, u16* __restrict__ vT, float* __restrict__ qb)
{
    __shared__ u16 As[128 * 64];
    __shared__ u16 Bs[128 * 64];
    f32x4 acc[4][4];
    #pragma unroll
    for (int i = 0; i < 4; i++)
        #pragma unroll
        for (int j = 0; j < 4; j++) acc[i][j] = (f32x4){0.f, 0.f, 0.f, 0.f};

    mm_tile_core(xnP + (size_t)blockIdx.x * 128 * 1536,
                 WuvT + (size_t)blockIdx.y * 128 * 1536, 1536, As, Bs, acc);

    const int lane = threadIdx.x & 63, wid = threadIdx.x >> 6;
    const int wr = wid >> 1, wc = wid & 1;
    const int r0 = (lane >> 4) * 4, c0 = lane & 15;
    #pragma unroll
    for (int i = 0; i < 4; i++) {
        #pragma unroll
        for (int j = 0; j < 4; j++) {
            const int col = blockIdx.y * 128 + wc * 64 + j * 16 + c0;
            const float bc = buv[col];
            #pragma unroll
            for (int r = 0; r < 4; r++) {
                const int row = blockIdx.x * 128 + wr * 64 + i * 16 + r0 + r;
                float val = silu_f(acc[i][j][r] + bc);
                if (col < E_) {
                    u[(size_t)row * E_ + col] = val;
                } else if (col < 2 * E_) {
                    const int e = col - E_, b = row >> 10, m = row & (N_ - 1);
                    u16 h = f2bf(val), l = f2bf(val - b2f(h));
                    u16* vr = vT + ((size_t)b * N_ + e) * 3072;
                    vr[m] = h; vr[1024 + m] = l; vr[2048 + m] = h;
                } else {
                    qb[(size_t)row * S_ + (col - 2 * E_)] = val;
                }
            }
        }
    }
}

// ---------------------------------------------------------------------------
// Kernel 4: gamma/beta affine + RoPE (unchanged, verified)
// ---------------------------------------------------------------------------
__global__ __launch_bounds__(256) void rope_kernel(
    float* __restrict__ qb, float* __restrict__ kb,
    const float* __restrict__ gamma, const float* __restrict__ beta,
    const float* __restrict__ sin_t, const float* __restrict__ cos_t)
{
    int row = blockIdx.x * 4 + (threadIdx.x >> 6);
    int i   = threadIdx.x & 63;
    int n   = row & (N_ - 1);
    size_t base = (size_t)row * S_;
    float b1 = qb[base + i];
    float b2 = qb[base + i + 64];
    float sn = sin_t[n * 64 + i];
    float cs = cos_t[n * 64 + i];
    float t1 = b1 * gamma[i]      + beta[i];
    float t2 = b2 * gamma[i + 64] + beta[i + 64];
    qb[base + i]      = t1 * cs - t2 * sn;
    qb[base + i + 64] = t2 * cs + t1 * sn;
    t1 = b1 * gamma[128 + i]      + beta[128 + i];
    t2 = b2 * gamma[128 + i + 64] + beta[128 + i + 64];
    kb[base + i]      = t1 * cs - t2 * sn;
    kb[base + i + 64] = t2 * cs + t1 * sn;
}

// ---------------------------------------------------------------------------
// Kernel 5: fp32 vector qk (verified core); epilogue emits A' split-bf16
// A-side layout per batch [n][K'=3072] at k'=m,1024+m,2048+m = hi,hi,lo
// ---------------------------------------------------------------------------
__global__ __launch_bounds__(256) void qk_kernel(
    const float* __restrict__ q, const float* __restrict__ k,
    u16* __restrict__ Aq)
{
    __shared__ float Qs[8][128];
    __shared__ float Ks[8][128];
    const int tid = threadIdx.x;
    const int bm = blockIdx.x, bn = blockIdx.y, b = blockIdx.z;
    const int tx = tid & 15, ty = tid >> 4;
    const int arow = tid >> 1, ak = (tid & 1) * 4;
    const float* Qp = q + (size_t)b * N_ * S_ + (size_t)(bm * 128 + arow) * S_ + ak;
    const float* Kp = k + (size_t)b * N_ * S_ + (size_t)(bn * 128 + arow) * S_ + ak;

    float acc[8][8];
    #pragma unroll
    for (int i = 0; i < 8; i++)
        #pragma unroll
        for (int j = 0; j < 8; j++) acc[i][j] = 0.0f;

    float4 a4 = *(const float4*)(Qp);
    float4 b4 = *(const float4*)(Kp);
    for (int kt = 0; kt < S_; kt += 8) {
        Qs[ak + 0][arow] = a4.x; Qs[ak + 1][arow] = a4.y;
        Qs[ak + 2][arow] = a4.z; Qs[ak + 3][arow] = a4.w;
        Ks[ak + 0][arow] = b4.x; Ks[ak + 1][arow] = b4.y;
        Ks[ak + 2][arow] = b4.z; Ks[ak + 3][arow] = b4.w;
        __syncthreads();
        const int ktn = (kt + 8 < S_) ? kt + 8 : kt;
        float4 a4n = *(const float4*)(Qp + ktn);
        float4 b4n = *(const float4*)(Kp + ktn);
        #pragma unroll
        for (int kk = 0; kk < 8; kk++) {
            float a[8], bb[8];
            *(float4*)&a[0]  = *(const float4*)&Qs[kk][ty * 8];
            *(float4*)&a[4]  = *(const float4*)&Qs[kk][ty * 8 + 4];
            *(float4*)&bb[0] = *(const float4*)&Ks[kk][tx * 8];
            *(float4*)&bb[4] = *(const float4*)&Ks[kk][tx * 8 + 4];
            #pragma unroll
            for (int i = 0; i < 8; i++)
                #pragma unroll
                for (int j = 0; j < 8; j++)
                    acc[i][j] += a[i] * bb[j];
        }
        __syncthreads();
        a4 = a4n; b4 = b4n;
    }

    const int row0 = bm * 128 + ty * 8;
    const int col0 = bn * 128 + tx * 8;
    u16* Ab = Aq + (size_t)b * N_ * 3072;
    #pragma unroll
    for (int i = 0; i < 8; i++) {
        u16* ar = Ab + (size_t)(row0 + i) * 3072;
        #pragma unroll
        for (int j = 0; j < 8; j++) {
            float t = acc[i][j] / 11.313708498984761f;
            t = fmaxf(t, 0.0f);
            t = t * t;
            u16 h = f2bf(t), l = f2bf(t - b2f(h));
            ar[col0 + j] = h; ar[1024 + col0 + j] = h; ar[2048 + col0 + j] = l;
        }
    }
}

// ---------------------------------------------------------------------------
// AV (MFMA): y = u .* (A@v); emits y' split-bf16 A-side [row][K'=3072]
// ---------------------------------------------------------------------------
__global__ __launch_bounds__(256) void av_mfma(
    const u16* __restrict__ Aq, const u16* __restrict__ vT,
    const float* __restrict__ u, u16* __restrict__ yP)
{
    __shared__ u16 As[128 * 64];
    __shared__ u16 Bs[128 * 64];
    f32x4 acc[4][4];
    #pragma unroll
    for (int i = 0; i < 4; i++)
        #pragma unroll
        for (int j = 0; j < 4; j++) acc[i][j] = (f32x4){0.f, 0.f, 0.f, 0.f};

    const int b = blockIdx.z;
    mm_tile_core(Aq + ((size_t)b * N_ + blockIdx.x * 128) * 3072,
                 vT + ((size_t)b * N_ + blockIdx.y * 128) * 3072, 3072,
                 As, Bs, acc);

    const int lane = threadIdx.x & 63, wid = threadIdx.x >> 6;
    const int wr = wid >> 1, wc = wid & 1;
    const int r0 = (lane >> 4) * 4, c0 = lane & 15;
    #pragma unroll
    for (int i = 0; i < 4; i++) {
        #pragma unroll
        for (int j = 0; j < 4; j++) {
            const int e = blockIdx.y * 128 + wc * 64 + j * 16 + c0;
            #pragma unroll
            for (int r = 0; r < 4; r++) {
                const int row = blockIdx.x * 128 + wr * 64 + i * 16 + r0 + r;
                const size_t gr = (size_t)b * N_ + row;
                float y = u[gr * E_ + e] * acc[i][j][r];
                u16 h = f2bf(y), l = f2bf(y - b2f(h));
                u16* yr = yP + gr * 3072;
                yr[e] = h; yr[1024 + e] = h; yr[2048 + e] = l;
            }
        }
    }
}

// ---------------------------------------------------------------------------
// Final (MFMA): out = y@Wo + bo + x
// ---------------------------------------------------------------------------
__global__ __launch_bounds__(256) void final_mfma(
    const u16* __restrict__ yP, const u16* __restrict__ WoT,
    const float* __restrict__ bo, const float* __restrict__ x,
    float* __restrict__ out)
{
    __shared__ u16 As[128 * 64];
    __shared__ u16 Bs[128 * 64];
    f32x4 acc[4][4];
    #pragma unroll
    for (int i = 0; i < 4; i++)
        #pragma unroll
        for (int j = 0; j < 4; j++) acc[i][j] = (f32x4){0.f, 0.f, 0.f, 0.f};

    mm_tile_core(yP + (size_t)blockIdx.x * 128 * 3072,
                 WoT + (size_t)blockIdx.y * 128 * 3072, 3072, As, Bs, acc);

    const int lane = threadIdx.x & 63, wid = threadIdx.x >> 6;
    const int wr = wid >> 1, wc = wid & 1;
    const int r0 = (lane >> 4) * 4, c0 = lane & 15;
    #pragma unroll
    for (int i = 0; i < 4; i++) {
        #pragma unroll
        for (int j = 0; j < 4; j++) {
            const int col = blockIdx.y * 128 + wc * 64 + j * 16 + c0;
            const float bc = bo[col];
            #pragma unroll
            for (int r = 0; r < 4; r++) {
                const int row = blockIdx.x * 128 + wr * 64 + i * 16 + r0 + r;
                out[(size_t)row * H_ + col] =
                    acc[i][j][r] + bc + x[(size_t)row * H_ + col];
            }
        }
    }
}

// ---------------------------------------------------------------------------
extern "C" void kernel_launch(void* const* d_in, const int* in_sizes, int n_in,
                              void* d_out, int out_size, void* d_ws, size_t ws_size,
                              hipStream_t stream)
{
    const float* x     = (const float*)d_in[0];
    const float* Wuv   = (const float*)d_in[1];
    const float* buv   = (const float*)d_in[2];
    const float* gamma = (const float*)d_in[3];
    const float* beta  = (const float*)d_in[4];
    const float* Wo    = (const float*)d_in[5];
    const float* bo    = (const float*)d_in[6];
    const float* g     = (const float*)d_in[7];
    float* out = (float*)d_out;

    // --- ws carve, ws_size-adaptive chunking -------------------------------
    const size_t fixedB = (size_t)R_ * 4 + 2 * 65536 * 4          // s + trig
                        + (size_t)NW_ * 1536 * 2                  // WuvT'
                        + (size_t)H_ * 3072 * 2;                  // WoT'
    const size_t perBatchB = 27262976ull;  // xn'+qb+kb+u+vT'+A'+y' per batch
    int c = 8;                             // cap: need(8) ~= 229 MB
    while (c > 1) {
        if (fixedB + (size_t)c * perBatchB <= ws_size) break;
        c >>= 1;
    }
    const int Rc = c * N_;

    char* p = (char*)d_ws;
    float* s_buf = (float*)p;  p += (size_t)R_ * 4;
    float* sin_t = (float*)p;  p += (size_t)N_ * 64 * 4;
    float* cos_t = (float*)p;  p += (size_t)N_ * 64 * 4;
    u16*   WuvT  = (u16*)p;    p += (size_t)NW_ * 1536 * 2;
    u16*   WoT   = (u16*)p;    p += (size_t)H_ * 3072 * 2;
    u16*   xnP   = (u16*)p;    p += (size_t)Rc * 1536 * 2;
    float* qb    = (float*)p;  p += (size_t)Rc * S_ * 4;
    float* kb    = (float*)p;  p += (size_t)Rc * S_ * 4;
    float* u_c   = (float*)p;  p += (size_t)Rc * E_ * 4;
    u16*   vT    = (u16*)p;    p += (size_t)Rc * 3072 * 2;
    u16*   Aq    = (u16*)p;    p += (size_t)Rc * 3072 * 2;
    u16*   yP    = (u16*)p;    p += (size_t)Rc * 3072 * 2;

    scale_kernel<<<R_ / 4, 256, 0, stream>>>(x, g, s_buf);
    trig_kernel<<<(N_ * 64) / 256, 256, 0, stream>>>(sin_t, cos_t);
    wuvt_kernel<<<H_, 256, 0, stream>>>(Wuv, WuvT);
    wot_kernel<<<E_, 256, 0, stream>>>(Wo, WoT);

    for (int b0 = 0; b0 < B_; b0 += c) {
        const size_t ro = (size_t)b0 * N_;
        xnp_kernel<<<(Rc * 512) / 256, 256, 0, stream>>>(
            x + ro * H_, s_buf + ro, xnP);
        gemm1_mfma<<<dim3(Rc / 128, NW_ / 128), 256, 0, stream>>>(
            xnP, WuvT, buv, u_c, vT, qb);
        rope_kernel<<<Rc / 4, 256, 0, stream>>>(
            qb, kb, gamma, beta, sin_t, cos_t);
        qk_kernel<<<dim3(N_ / 128, N_ / 128, c), 256, 0, stream>>>(
            qb, kb, Aq);
        av_mfma<<<dim3(N_ / 128, N_ / 128, c), 256, 0, stream>>>(
            Aq, vT, u_c, yP);
        final_mfma<<<dim3(Rc / 128, H_ / 128), 256, 0, stream>>>(
            yP, WoT, bo, x + ro * H_, out + ro * H_);
    }
}

// Round 7
// 1561.100 us; speedup vs baseline: 1.5079x; 1.0221x over previous
//
#include <hip/hip_runtime.h>
#include <cstdint>
#include <cstddef>

// Problem constants
#define B_   32
#define N_   1024
#define H_   512
#define E_   1024
#define S_   128
#define NW_  2176            // 2E + S
#define R_   (B_ * N_)       // 32768 rows total

typedef unsigned short u16;
typedef __attribute__((ext_vector_type(8))) short bf16x8;
typedef __attribute__((ext_vector_type(4))) float f32x4;

static __device__ __forceinline__ float silu_f(float x) {
    return x / (1.0f + expf(-x));
}
// bf16 round-to-nearest-even split helpers (inputs finite)
static __device__ __forceinline__ u16 f2bf(float f) {
    unsigned u = __float_as_uint(f);
    unsigned r = u + 0x7fffu + ((u >> 16) & 1u);
    return (u16)(r >> 16);
}
static __device__ __forceinline__ float b2f(u16 h) {
    return __uint_as_float(((unsigned)h) << 16);
}

// direct global->LDS 16B async copy (per-lane global src, linear LDS dest)
#define GLOAD_LDS16(SRC, DST)                                                  \
    __builtin_amdgcn_global_load_lds(                                          \
        (const __attribute__((address_space(1))) void*)(SRC),                  \
        (__attribute__((address_space(3))) void*)(DST), 16, 0, 0)

// ---------------------------------------------------------------------------
// Shared MFMA core, 2-phase double-buffered (T3-minimum): while computing
// K-tile t from LDS buffer `cur`, K-tile t+1's global_load_lds are already in
// flight into buffer cur^1; the single __syncthreads() per step drains them
// AFTER compute, hiding staging latency. LDS tiles [128][64] bf16,
// XOR-swizzled (byte ^= (row&7)<<4) with inverse-swizzled global source
// (rule #21). 4 waves, each owns a 64x64 quadrant (4x4 16x16x32 frags).
// ---------------------------------------------------------------------------
#define STAGE(BUF, KT)                                                         \
    {                                                                          \
        _Pragma("unroll")                                                      \
        for (int s = 0; s < 4; s++) {                                          \
            const int row = s * 32 + trow;                                     \
            const int kb  = p ^ ((row & 7) << 4);                              \
            GLOAD_LDS16(Atile + (size_t)row * KP + (KT) + (kb >> 1),           \
                        (char*)As + (BUF) * 16384 + s * 4096 + wid * 1024);    \
            GLOAD_LDS16(Btile + (size_t)row * KP + (KT) + (kb >> 1),           \
                        (char*)Bs + (BUF) * 16384 + s * 4096 + wid * 1024);    \
        }                                                                      \
    }

__device__ __forceinline__ void mm_tile_core(
    const u16* __restrict__ Atile, const u16* __restrict__ Btile,
    int KP, u16* As, u16* Bs, f32x4 acc[4][4])
{
    const int tid  = threadIdx.x;
    const int lane = tid & 63, wid = tid >> 6;
    const int wr = wid >> 1, wc = wid & 1;
    const int trow = tid >> 3;            // row within 32-row staging block
    const int p    = (tid & 7) * 16;      // physical byte offset within row

    STAGE(0, 0);
    __syncthreads();                      // buffer 0 ready
    int cur = 0;
    for (int kt = 0; kt < KP; kt += 64) {
        if (kt + 64 < KP) STAGE(cur ^ 1, kt + 64);   // prefetch next K-tile
        const char* Ab = (const char*)As + cur * 16384;
        const char* Bb = (const char*)Bs + cur * 16384;
        #pragma unroll
        for (int kk = 0; kk < 2; kk++) {
            const int kbyte = kk * 64 + (lane >> 4) * 16;
            bf16x8 af[4], bf[4];
            #pragma unroll
            for (int f = 0; f < 4; f++) {
                const int ra = wr * 64 + f * 16 + (lane & 15);
                af[f] = *(const bf16x8*)(Ab + ra * 128 +
                                         (kbyte ^ ((ra & 7) << 4)));
                const int rb = wc * 64 + f * 16 + (lane & 15);
                bf[f] = *(const bf16x8*)(Bb + rb * 128 +
                                         (kbyte ^ ((rb & 7) << 4)));
            }
            #pragma unroll
            for (int i = 0; i < 4; i++)
                #pragma unroll
                for (int j = 0; j < 4; j++)
                    acc[i][j] = __builtin_amdgcn_mfma_f32_16x16x32_bf16(
                        af[i], bf[j], acc[i][j], 0, 0, 0);
        }
        __syncthreads();    // drains prefetch vmcnt + protects cur reuse
        cur ^= 1;
    }
}

// ---------------------------------------------------------------------------
// Kernel 1: per-row scale factor (unchanged, verified)
// ---------------------------------------------------------------------------
__global__ __launch_bounds__(256) void scale_kernel(
    const float* __restrict__ x, const float* __restrict__ g,
    float* __restrict__ s)
{
    int row  = blockIdx.x * 4 + (threadIdx.x >> 6);
    int lane = threadIdx.x & 63;
    const float4* xr = (const float4*)(x + (size_t)row * H_);
    float4 a = xr[lane];
    float4 b = xr[lane + 64];
    float acc = a.x*a.x + a.y*a.y + a.z*a.z + a.w*a.w
              + b.x*b.x + b.y*b.y + b.z*b.z + b.w*b.w;
    #pragma unroll
    for (int off = 1; off < 64; off <<= 1)
        acc += __shfl_xor(acc, off);
    if (lane == 0) {
        float norm = sqrtf(acc) * 0.044194173824159216f;
        s[row] = g[0] / fmaxf(norm, 1e-5f);
    }
}

// ---------------------------------------------------------------------------
// Kernel 2: RoPE trig tables in fp64 (unchanged, verified)
// ---------------------------------------------------------------------------
__global__ __launch_bounds__(256) void trig_kernel(
    float* __restrict__ sin_t, float* __restrict__ cos_t)
{
    int idx = blockIdx.x * 256 + threadIdx.x;
    int n = idx >> 6;
    int i = idx & 63;
    double invf_d = pow(10000.0, (double)i * (1.0 / 64.0));
    float  invf   = (float)invf_d;
    float  arg    = (float)n * invf;
    sin_t[idx] = (float)sin((double)arg);
    cos_t[idx] = (float)cos((double)arg);
}

// ---------------------------------------------------------------------------
// Conversion: xn' = split(x*s)  A-side layout [hi|hi|lo], K'=1536
// ---------------------------------------------------------------------------
__global__ __launch_bounds__(256) void xnp_kernel(
    const float* __restrict__ x, const float* __restrict__ s,
    u16* __restrict__ xnP)
{
    int idx = blockIdx.x * 256 + threadIdx.x;    // Rc*512 elements
    int r = idx >> 9, k = idx & 511;
    float v = x[(size_t)r * H_ + k] * s[r];
    u16 h = f2bf(v), l = f2bf(v - b2f(h));
    u16* xr = xnP + (size_t)r * 1536;
    xr[k] = h; xr[512 + k] = h; xr[1024 + k] = l;
}

// ---------------------------------------------------------------------------
// Conversion: WuvT' B-side layout [hi|lo|hi], [col 2176][K'=1536] (once)
// ---------------------------------------------------------------------------
__global__ __launch_bounds__(256) void wuvt_kernel(
    const float* __restrict__ Wuv, u16* __restrict__ WuvT)
{
    int k = blockIdx.x;                           // 0..511
    for (int c = threadIdx.x; c < NW_; c += 256) {
        float v = Wuv[(size_t)k * NW_ + c];
        u16 h = f2bf(v), l = f2bf(v - b2f(h));
        u16* wr = WuvT + (size_t)c * 1536;
        wr[k] = h; wr[512 + k] = l; wr[1024 + k] = h;
    }
}

// ---------------------------------------------------------------------------
// Conversion: WoT' B-side layout [hi|lo|hi], [col 512][K'=3072] (once)
// ---------------------------------------------------------------------------
__global__ __launch_bounds__(256) void wot_kernel(
    const float* __restrict__ Wo, u16* __restrict__ WoT)
{
    int k = blockIdx.x;                           // 0..1023
    for (int c = threadIdx.x; c < H_; c += 256) {
        float v = Wo[(size_t)k * H_ + c];
        u16 h = f2bf(v), l = f2bf(v - b2f(h));
        u16* wr = WoT + (size_t)c * 3072;
        wr[k] = h; wr[1024 + k] = l; wr[2048 + k] = h;
    }
}

// ---------------------------------------------------------------------------
// GEMM1 (MFMA): silu(xn@Wuv+buv) -> u fp32 | v split-bf16 (B-side, per-batch
// [e][K'=3072] at k'=m,1024+m,2048+m = hi,lo,hi) | qb fp32
// ---------------------------------------------------------------------------
__global__ __launch_bounds__(256) void gemm1_mfma(
    const u16* __restrict__ xnP, const u16* __restrict__ WuvT,
    const float* __restrict__ buv,
    float* __restrict__ u, u16* __restrict__ vT, float* __restrict__ qb)
{
    __shared__ u16 As[2 * 128 * 64];
    __shared__ u16 Bs[2 * 128 * 64];
    f32x4 acc[4][4];
    #pragma unroll
    for (int i = 0; i < 4; i++)
        #pragma unroll
        for (int j = 0; j < 4; j++) acc[i][j] = (f32x4){0.f, 0.f, 0.f, 0.f};

    mm_tile_core(xnP + (size_t)blockIdx.x * 128 * 1536,
                 WuvT + (size_t)blockIdx.y * 128 * 1536, 1536, As, Bs, acc);

    const int lane = threadIdx.x & 63, wid = threadIdx.x >> 6;
    const int wr = wid >> 1, wc = wid & 1;
    const int r0 = (lane >> 4) * 4, c0 = lane & 15;
    #pragma unroll
    for (int i = 0; i < 4; i++) {
        #pragma unroll
        for (int j = 0; j < 4; j++) {
            const int col = blockIdx.y * 128 + wc * 64 + j * 16 + c0;
            const float bc = buv[col];
            #pragma unroll
            for (int r = 0; r < 4; r++) {
                const int row = blockIdx.x * 128 + wr * 64 + i * 16 + r0 + r;
                float val = silu_f(acc[i][j][r] + bc);
                if (col < E_) {
                    u[(size_t)row * E_ + col] = val;
                } else if (col < 2 * E_) {
                    const int e = col - E_, b = row >> 10, m = row & (N_ - 1);
                    u16 h = f2bf(val), l = f2bf(val - b2f(h));
                    u16* vr = vT + ((size_t)b * N_ + e) * 3072;
                    vr[m] = h; vr[1024 + m] = l; vr[2048 + m] = h;
                } else {
                    qb[(size_t)row * S_ + (col - 2 * E_)] = val;
                }
            }
        }
    }
}

// ---------------------------------------------------------------------------
// Kernel 4: gamma/beta affine + RoPE (unchanged, verified)
// ---------------------------------------------------------------------------
__global__ __launch_bounds__(256) void rope_kernel(
    float* __restrict__ qb, float* __restrict__ kb,
    const float* __restrict__ gamma, const float* __restrict__ beta,
    const float* __restrict__ sin_t, const float* __restrict__ cos_t)
{
    int row = blockIdx.x * 4 + (threadIdx.x >> 6);
    int i   = threadIdx.x & 63;
    int n   = row & (N_ - 1);
    size_t base = (size_t)row * S_;
    float b1 = qb[base + i];
    float b2 = qb[base + i + 64];
    float sn = sin_t[n * 64 + i];
    float cs = cos_t[n * 64 + i];
    float t1 = b1 * gamma[i]      + beta[i];
    float t2 = b2 * gamma[i + 64] + beta[i + 64];
    qb[base + i]      = t1 * cs - t2 * sn;
    qb[base + i + 64] = t2 * cs + t1 * sn;
    t1 = b1 * gamma[128 + i]      + beta[128 + i];
    t2 = b2 * gamma[128 + i + 64] + beta[128 + i + 64];
    kb[base + i]      = t1 * cs - t2 * sn;
    kb[base + i + 64] = t2 * cs + t1 * sn;
}

// ---------------------------------------------------------------------------
// Kernel 5: fp32 vector qk (verified core); epilogue emits A' split-bf16
// A-side layout per batch [n][K'=3072] at k'=m,1024+m,2048+m = hi,hi,lo
// ---------------------------------------------------------------------------
__global__ __launch_bounds__(256) void qk_kernel(
    const float* __restrict__ q, const float* __restrict__ k,
    u16* __restrict__ Aq)
{
    __shared__ float Qs[8][128];
    __shared__ float Ks[8][128];
    const int tid = threadIdx.x;
    const int bm = blockIdx.x, bn = blockIdx.y, b = blockIdx.z;
    const int tx = tid & 15, ty = tid >> 4;
    const int arow = tid >> 1, ak = (tid & 1) * 4;
    const float* Qp = q + (size_t)b * N_ * S_ + (size_t)(bm * 128 + arow) * S_ + ak;
    const float* Kp = k + (size_t)b * N_ * S_ + (size_t)(bn * 128 + arow) * S_ + ak;

    float acc[8][8];
    #pragma unroll
    for (int i = 0; i < 8; i++)
        #pragma unroll
        for (int j = 0; j < 8; j++) acc[i][j] = 0.0f;

    float4 a4 = *(const float4*)(Qp);
    float4 b4 = *(const float4*)(Kp);
    for (int kt = 0; kt < S_; kt += 8) {
        Qs[ak + 0][arow] = a4.x; Qs[ak + 1][arow] = a4.y;
        Qs[ak + 2][arow] = a4.z; Qs[ak + 3][arow] = a4.w;
        Ks[ak + 0][arow] = b4.x; Ks[ak + 1][arow] = b4.y;
        Ks[ak + 2][arow] = b4.z; Ks[ak + 3][arow] = b4.w;
        __syncthreads();
        const int ktn = (kt + 8 < S_) ? kt + 8 : kt;
        float4 a4n = *(const float4*)(Qp + ktn);
        float4 b4n = *(const float4*)(Kp + ktn);
        #pragma unroll
        for (int kk = 0; kk < 8; kk++) {
            float a[8], bb[8];
            *(float4*)&a[0]  = *(const float4*)&Qs[kk][ty * 8];
            *(float4*)&a[4]  = *(const float4*)&Qs[kk][ty * 8 + 4];
            *(float4*)&bb[0] = *(const float4*)&Ks[kk][tx * 8];
            *(float4*)&bb[4] = *(const float4*)&Ks[kk][tx * 8 + 4];
            #pragma unroll
            for (int i = 0; i < 8; i++)
                #pragma unroll
                for (int j = 0; j < 8; j++)
                    acc[i][j] += a[i] * bb[j];
        }
        __syncthreads();
        a4 = a4n; b4 = b4n;
    }

    const int row0 = bm * 128 + ty * 8;
    const int col0 = bn * 128 + tx * 8;
    u16* Ab = Aq + (size_t)b * N_ * 3072;
    #pragma unroll
    for (int i = 0; i < 8; i++) {
        u16* ar = Ab + (size_t)(row0 + i) * 3072;
        #pragma unroll
        for (int j = 0; j < 8; j++) {
            float t = acc[i][j] / 11.313708498984761f;
            t = fmaxf(t, 0.0f);
            t = t * t;
            u16 h = f2bf(t), l = f2bf(t - b2f(h));
            ar[col0 + j] = h; ar[1024 + col0 + j] = h; ar[2048 + col0 + j] = l;
        }
    }
}

// ---------------------------------------------------------------------------
// AV (MFMA): y = u .* (A@v); emits y' split-bf16 A-side [row][K'=3072]
// ---------------------------------------------------------------------------
__global__ __launch_bounds__(256) void av_mfma(
    const u16* __restrict__ Aq, const u16* __restrict__ vT,
    const float* __restrict__ u, u16* __restrict__ yP)
{
    __shared__ u16 As[2 * 128 * 64];
    __shared__ u16 Bs[2 * 128 * 64];
    f32x4 acc[4][4];
    #pragma unroll
    for (int i = 0; i < 4; i++)
        #pragma unroll
        for (int j = 0; j < 4; j++) acc[i][j] = (f32x4){0.f, 0.f, 0.f, 0.f};

    const int b = blockIdx.z;
    mm_tile_core(Aq + ((size_t)b * N_ + blockIdx.x * 128) * 3072,
                 vT + ((size_t)b * N_ + blockIdx.y * 128) * 3072, 3072,
                 As, Bs, acc);

    const int lane = threadIdx.x & 63, wid = threadIdx.x >> 6;
    const int wr = wid >> 1, wc = wid & 1;
    const int r0 = (lane >> 4) * 4, c0 = lane & 15;
    #pragma unroll
    for (int i = 0; i < 4; i++) {
        #pragma unroll
        for (int j = 0; j < 4; j++) {
            const int e = blockIdx.y * 128 + wc * 64 + j * 16 + c0;
            #pragma unroll
            for (int r = 0; r < 4; r++) {
                const int row = blockIdx.x * 128 + wr * 64 + i * 16 + r0 + r;
                const size_t gr = (size_t)b * N_ + row;
                float y = u[gr * E_ + e] * acc[i][j][r];
                u16 h = f2bf(y), l = f2bf(y - b2f(h));
                u16* yr = yP + gr * 3072;
                yr[e] = h; yr[1024 + e] = h; yr[2048 + e] = l;
            }
        }
    }
}

// ---------------------------------------------------------------------------
// Final (MFMA): out = y@Wo + bo + x
// ---------------------------------------------------------------------------
__global__ __launch_bounds__(256) void final_mfma(
    const u16* __restrict__ yP, const u16* __restrict__ WoT,
    const float* __restrict__ bo, const float* __restrict__ x,
    float* __restrict__ out)
{
    __shared__ u16 As[2 * 128 * 64];
    __shared__ u16 Bs[2 * 128 * 64];
    f32x4 acc[4][4];
    #pragma unroll
    for (int i = 0; i < 4; i++)
        #pragma unroll
        for (int j = 0; j < 4; j++) acc[i][j] = (f32x4){0.f, 0.f, 0.f, 0.f};

    mm_tile_core(yP + (size_t)blockIdx.x * 128 * 3072,
                 WoT + (size_t)blockIdx.y * 128 * 3072, 3072, As, Bs, acc);

    const int lane = threadIdx.x & 63, wid = threadIdx.x >> 6;
    const int wr = wid >> 1, wc = wid & 1;
    const int r0 = (lane >> 4) * 4, c0 = lane & 15;
    #pragma unroll
    for (int i = 0; i < 4; i++) {
        #pragma unroll
        for (int j = 0; j < 4; j++) {
            const int col = blockIdx.y * 128 + wc * 64 + j * 16 + c0;
            const float bc = bo[col];
            #pragma unroll
            for (int r = 0; r < 4; r++) {
                const int row = blockIdx.x * 128 + wr * 64 + i * 16 + r0 + r;
                out[(size_t)row * H_ + col] =
                    acc[i][j][r] + bc + x[(size_t)row * H_ + col];
            }
        }
    }
}

// ---------------------------------------------------------------------------
extern "C" void kernel_launch(void* const* d_in, const int* in_sizes, int n_in,
                              void* d_out, int out_size, void* d_ws, size_t ws_size,
                              hipStream_t stream)
{
    const float* x     = (const float*)d_in[0];
    const float* Wuv   = (const float*)d_in[1];
    const float* buv   = (const float*)d_in[2];
    const float* gamma = (const float*)d_in[3];
    const float* beta  = (const float*)d_in[4];
    const float* Wo    = (const float*)d_in[5];
    const float* bo    = (const float*)d_in[6];
    const float* g     = (const float*)d_in[7];
    float* out = (float*)d_out;

    // --- ws carve, ws_size-adaptive chunking -------------------------------
    const size_t fixedB = (size_t)R_ * 4 + 2 * 65536 * 4          // s + trig
                        + (size_t)NW_ * 1536 * 2                  // WuvT'
                        + (size_t)H_ * 3072 * 2;                  // WoT'
    const size_t perBatchB = 27262976ull;  // xn'+qb+kb+u+vT'+A'+y' per batch
    int c = 8;                             // cap: need(8) ~= 229 MB
    while (c > 1) {
        if (fixedB + (size_t)c * perBatchB <= ws_size) break;
        c >>= 1;
    }
    const int Rc = c * N_;

    char* p = (char*)d_ws;
    float* s_buf = (float*)p;  p += (size_t)R_ * 4;
    float* sin_t = (float*)p;  p += (size_t)N_ * 64 * 4;
    float* cos_t = (float*)p;  p += (size_t)N_ * 64 * 4;
    u16*   WuvT  = (u16*)p;    p += (size_t)NW_ * 1536 * 2;
    u16*   WoT   = (u16*)p;    p += (size_t)H_ * 3072 * 2;
    u16*   xnP   = (u16*)p;    p += (size_t)Rc * 1536 * 2;
    float* qb    = (float*)p;  p += (size_t)Rc * S_ * 4;
    float* kb    = (float*)p;  p += (size_t)Rc * S_ * 4;
    float* u_c   = (float*)p;  p += (size_t)Rc * E_ * 4;
    u16*   vT    = (u16*)p;    p += (size_t)Rc * 3072 * 2;
    u16*   Aq    = (u16*)p;    p += (size_t)Rc * 3072 * 2;
    u16*   yP    = (u16*)p;    p += (size_t)Rc * 3072 * 2;

    scale_kernel<<<R_ / 4, 256, 0, stream>>>(x, g, s_buf);
    trig_kernel<<<(N_ * 64) / 256, 256, 0, stream>>>(sin_t, cos_t);
    wuvt_kernel<<<H_, 256, 0, stream>>>(Wuv, WuvT);
    wot_kernel<<<E_, 256, 0, stream>>>(Wo, WoT);

    for (int b0 = 0; b0 < B_; b0 += c) {
        const size_t ro = (size_t)b0 * N_;
        xnp_kernel<<<(Rc * 512) / 256, 256, 0, stream>>>(
            x + ro * H_, s_buf + ro, xnP);
        gemm1_mfma<<<dim3(Rc / 128, NW_ / 128), 256, 0, stream>>>(
            xnP, WuvT, buv, u_c, vT, qb);
        rope_kernel<<<Rc / 4, 256, 0, stream>>>(
            qb, kb, gamma, beta, sin_t, cos_t);
        qk_kernel<<<dim3(N_ / 128, N_ / 128, c), 256, 0, stream>>>(
            qb, kb, Aq);
        av_mfma<<<dim3(N_ / 128, N_ / 128, c), 256, 0, stream>>>(
            Aq, vT, u_c, yP);
        final_mfma<<<dim3(Rc / 128, H_ / 128), 256, 0, stream>>>(
            yP, WoT, bo, x + ro * H_, out + ro * H_);
    }
}

// Round 8
// 1512.197 us; speedup vs baseline: 1.5566x; 1.0323x over previous
//
#include <hip/hip_runtime.h>
#include <cstdint>
#include <cstddef>

// Problem constants
#define B_   32
#define N_   1024
#define H_   512
#define E_   1024
#define S_   128
#define NW_  2176            // 2E + S
#define R_   (B_ * N_)       // 32768 rows total

typedef unsigned short u16;
typedef __attribute__((ext_vector_type(8))) short bf16x8;
typedef __attribute__((ext_vector_type(4))) float f32x4;

static __device__ __forceinline__ float silu_f(float x) {
    return x / (1.0f + expf(-x));
}
// bf16 round-to-nearest-even split helpers (inputs finite)
static __device__ __forceinline__ u16 f2bf(float f) {
    unsigned u = __float_as_uint(f);
    unsigned r = u + 0x7fffu + ((u >> 16) & 1u);
    return (u16)(r >> 16);
}
static __device__ __forceinline__ float b2f(u16 h) {
    return __uint_as_float(((unsigned)h) << 16);
}

// direct global->LDS 16B async copy (per-lane global src, linear LDS dest:
// HW writes wave-uniform base + lane*16)
#define GLOAD_LDS16(SRC, DST)                                                  \
    __builtin_amdgcn_global_load_lds(                                          \
        (const __attribute__((address_space(1))) void*)(SRC),                  \
        (__attribute__((address_space(3))) void*)(DST), 16, 0, 0)

// ---------------------------------------------------------------------------
// Shared MFMA core — m97 proportions (the ladder's verified 912 TF config):
// 128x128 tile, BK=32, single-buffered 16 KB LDS, 2 barriers per K-step.
// Latency hiding comes from ~4 independent resident blocks/CU (m114), not
// in-block pipelining (r7 post-mortem: dbuf at 64KB LDS was neutral — m132
// trap). LDS rows are 64 B at BK=32 -> linear layout is conflict-minimal
// (uniform 8 accesses/bank per 1 KB ds_read_b128); no swizzle needed.
// 4 waves, each owns a 64x64 quadrant (4x4 16x16x32 bf16 fragments).
// ---------------------------------------------------------------------------
__device__ __forceinline__ void mm_tile_core(
    const u16* __restrict__ Atile, const u16* __restrict__ Btile,
    int KP, u16* As, u16* Bs, f32x4 acc[4][4])
{
    const int tid  = threadIdx.x;
    const int lane = tid & 63, wid = tid >> 6;
    const int wr = wid >> 1, wc = wid & 1;
    const int srow = tid >> 2;            // staging row 0..63 (and +64)
    const int scol = (tid & 3) * 8;       // u16 offset within 32-elem row
    const int wbase = wid * 1024;         // byte base per wave (64 lanes*16B)

    for (int kt = 0; kt < KP; kt += 32) {
        // stage A,B tiles: 4 x global_load_lds_dwordx4 per thread
        GLOAD_LDS16(Atile + (size_t)srow * KP + kt + scol,
                    (char*)As + wbase);
        GLOAD_LDS16(Atile + (size_t)(srow + 64) * KP + kt + scol,
                    (char*)As + 4096 + wbase);
        GLOAD_LDS16(Btile + (size_t)srow * KP + kt + scol,
                    (char*)Bs + wbase);
        GLOAD_LDS16(Btile + (size_t)(srow + 64) * KP + kt + scol,
                    (char*)Bs + 4096 + wbase);
        __syncthreads();                  // drains vmcnt -> LDS ready

        const int kb = (lane >> 4) * 16;  // byte chunk within 64 B row
        bf16x8 af[4], bf[4];
        #pragma unroll
        for (int f = 0; f < 4; f++) {
            const int ra = wr * 64 + f * 16 + (lane & 15);
            af[f] = *(const bf16x8*)((const char*)As + ra * 64 + kb);
            const int rb = wc * 64 + f * 16 + (lane & 15);
            bf[f] = *(const bf16x8*)((const char*)Bs + rb * 64 + kb);
        }
        #pragma unroll
        for (int i = 0; i < 4; i++)
            #pragma unroll
            for (int j = 0; j < 4; j++)
                acc[i][j] = __builtin_amdgcn_mfma_f32_16x16x32_bf16(
                    af[i], bf[j], acc[i][j], 0, 0, 0);
        __syncthreads();                  // protect LDS overwrite next iter
    }
}

// ---------------------------------------------------------------------------
// Kernel 1: per-row scale factor (unchanged, verified)
// ---------------------------------------------------------------------------
__global__ __launch_bounds__(256) void scale_kernel(
    const float* __restrict__ x, const float* __restrict__ g,
    float* __restrict__ s)
{
    int row  = blockIdx.x * 4 + (threadIdx.x >> 6);
    int lane = threadIdx.x & 63;
    const float4* xr = (const float4*)(x + (size_t)row * H_);
    float4 a = xr[lane];
    float4 b = xr[lane + 64];
    float acc = a.x*a.x + a.y*a.y + a.z*a.z + a.w*a.w
              + b.x*b.x + b.y*b.y + b.z*b.z + b.w*b.w;
    #pragma unroll
    for (int off = 1; off < 64; off <<= 1)
        acc += __shfl_xor(acc, off);
    if (lane == 0) {
        float norm = sqrtf(acc) * 0.044194173824159216f;
        s[row] = g[0] / fmaxf(norm, 1e-5f);
    }
}

// ---------------------------------------------------------------------------
// Kernel 2: RoPE trig tables in fp64 (unchanged, verified)
// ---------------------------------------------------------------------------
__global__ __launch_bounds__(256) void trig_kernel(
    float* __restrict__ sin_t, float* __restrict__ cos_t)
{
    int idx = blockIdx.x * 256 + threadIdx.x;
    int n = idx >> 6;
    int i = idx & 63;
    double invf_d = pow(10000.0, (double)i * (1.0 / 64.0));
    float  invf   = (float)invf_d;
    float  arg    = (float)n * invf;
    sin_t[idx] = (float)sin((double)arg);
    cos_t[idx] = (float)cos((double)arg);
}

// ---------------------------------------------------------------------------
// Conversion: xn' = split(x*s)  A-side layout [hi|hi|lo], K'=1536
// ---------------------------------------------------------------------------
__global__ __launch_bounds__(256) void xnp_kernel(
    const float* __restrict__ x, const float* __restrict__ s,
    u16* __restrict__ xnP)
{
    int idx = blockIdx.x * 256 + threadIdx.x;    // Rc*512 elements
    int r = idx >> 9, k = idx & 511;
    float v = x[(size_t)r * H_ + k] * s[r];
    u16 h = f2bf(v), l = f2bf(v - b2f(h));
    u16* xr = xnP + (size_t)r * 1536;
    xr[k] = h; xr[512 + k] = h; xr[1024 + k] = l;
}

// ---------------------------------------------------------------------------
// Conversion: WuvT' B-side layout [hi|lo|hi], [col 2176][K'=1536] (once)
// ---------------------------------------------------------------------------
__global__ __launch_bounds__(256) void wuvt_kernel(
    const float* __restrict__ Wuv, u16* __restrict__ WuvT)
{
    int k = blockIdx.x;                           // 0..511
    for (int c = threadIdx.x; c < NW_; c += 256) {
        float v = Wuv[(size_t)k * NW_ + c];
        u16 h = f2bf(v), l = f2bf(v - b2f(h));
        u16* wr = WuvT + (size_t)c * 1536;
        wr[k] = h; wr[512 + k] = l; wr[1024 + k] = h;
    }
}

// ---------------------------------------------------------------------------
// Conversion: WoT' B-side layout [hi|lo|hi], [col 512][K'=3072] (once)
// ---------------------------------------------------------------------------
__global__ __launch_bounds__(256) void wot_kernel(
    const float* __restrict__ Wo, u16* __restrict__ WoT)
{
    int k = blockIdx.x;                           // 0..1023
    for (int c = threadIdx.x; c < H_; c += 256) {
        float v = Wo[(size_t)k * H_ + c];
        u16 h = f2bf(v), l = f2bf(v - b2f(h));
        u16* wr = WoT + (size_t)c * 3072;
        wr[k] = h; wr[1024 + k] = l; wr[2048 + k] = h;
    }
}

// ---------------------------------------------------------------------------
// GEMM1 (MFMA): silu(xn@Wuv+buv) -> u fp32 | v split-bf16 (B-side, per-batch
// [e][K'=3072] at k'=m,1024+m,2048+m = hi,lo,hi) | qb fp32
// ---------------------------------------------------------------------------
__global__ __launch_bounds__(256) void gemm1_mfma(
    const u16* __restrict__ xnP, const u16* __restrict__ WuvT,
    const float* __restrict__ buv,
    float* __restrict__ u, u16* __restrict__ vT, float* __restrict__ qb)
{
    __shared__ u16 As[128 * 32];
    __shared__ u16 Bs[128 * 32];
    f32x4 acc[4][4];
    #pragma unroll
    for (int i = 0; i < 4; i++)
        #pragma unroll
        for (int j = 0; j < 4; j++) acc[i][j] = (f32x4){0.f, 0.f, 0.f, 0.f};

    mm_tile_core(xnP + (size_t)blockIdx.x * 128 * 1536,
                 WuvT + (size_t)blockIdx.y * 128 * 1536, 1536, As, Bs, acc);

    const int lane = threadIdx.x & 63, wid = threadIdx.x >> 6;
    const int wr = wid >> 1, wc = wid & 1;
    const int r0 = (lane >> 4) * 4, c0 = lane & 15;
    #pragma unroll
    for (int i = 0; i < 4; i++) {
        #pragma unroll
        for (int j = 0; j < 4; j++) {
            const int col = blockIdx.y * 128 + wc * 64 + j * 16 + c0;
            const float bc = buv[col];
            #pragma unroll
            for (int r = 0; r < 4; r++) {
                const int row = blockIdx.x * 128 + wr * 64 + i * 16 + r0 + r;
                float val = silu_f(acc[i][j][r] + bc);
                if (col < E_) {
                    u[(size_t)row * E_ + col] = val;
                } else if (col < 2 * E_) {
                    const int e = col - E_, b = row >> 10, m = row & (N_ - 1);
                    u16 h = f2bf(val), l = f2bf(val - b2f(h));
                    u16* vr = vT + ((size_t)b * N_ + e) * 3072;
                    vr[m] = h; vr[1024 + m] = l; vr[2048 + m] = h;
                } else {
                    qb[(size_t)row * S_ + (col - 2 * E_)] = val;
                }
            }
        }
    }
}

// ---------------------------------------------------------------------------
// Kernel 4: gamma/beta affine + RoPE (unchanged, verified)
// ---------------------------------------------------------------------------
__global__ __launch_bounds__(256) void rope_kernel(
    float* __restrict__ qb, float* __restrict__ kb,
    const float* __restrict__ gamma, const float* __restrict__ beta,
    const float* __restrict__ sin_t, const float* __restrict__ cos_t)
{
    int row = blockIdx.x * 4 + (threadIdx.x >> 6);
    int i   = threadIdx.x & 63;
    int n   = row & (N_ - 1);
    size_t base = (size_t)row * S_;
    float b1 = qb[base + i];
    float b2 = qb[base + i + 64];
    float sn = sin_t[n * 64 + i];
    float cs = cos_t[n * 64 + i];
    float t1 = b1 * gamma[i]      + beta[i];
    float t2 = b2 * gamma[i + 64] + beta[i + 64];
    qb[base + i]      = t1 * cs - t2 * sn;
    qb[base + i + 64] = t2 * cs + t1 * sn;
    t1 = b1 * gamma[128 + i]      + beta[128 + i];
    t2 = b2 * gamma[128 + i + 64] + beta[128 + i + 64];
    kb[base + i]      = t1 * cs - t2 * sn;
    kb[base + i + 64] = t2 * cs + t1 * sn;
}

// ---------------------------------------------------------------------------
// Kernel 5: fp32 vector qk (verified core); epilogue emits A' split-bf16
// A-side layout per batch [n][K'=3072] at k'=m,1024+m,2048+m = hi,hi,lo
// ---------------------------------------------------------------------------
__global__ __launch_bounds__(256) void qk_kernel(
    const float* __restrict__ q, const float* __restrict__ k,
    u16* __restrict__ Aq)
{
    __shared__ float Qs[8][128];
    __shared__ float Ks[8][128];
    const int tid = threadIdx.x;
    const int bm = blockIdx.x, bn = blockIdx.y, b = blockIdx.z;
    const int tx = tid & 15, ty = tid >> 4;
    const int arow = tid >> 1, ak = (tid & 1) * 4;
    const float* Qp = q + (size_t)b * N_ * S_ + (size_t)(bm * 128 + arow) * S_ + ak;
    const float* Kp = k + (size_t)b * N_ * S_ + (size_t)(bn * 128 + arow) * S_ + ak;

    float acc[8][8];
    #pragma unroll
    for (int i = 0; i < 8; i++)
        #pragma unroll
        for (int j = 0; j < 8; j++) acc[i][j] = 0.0f;

    float4 a4 = *(const float4*)(Qp);
    float4 b4 = *(const float4*)(Kp);
    for (int kt = 0; kt < S_; kt += 8) {
        Qs[ak + 0][arow] = a4.x; Qs[ak + 1][arow] = a4.y;
        Qs[ak + 2][arow] = a4.z; Qs[ak + 3][arow] = a4.w;
        Ks[ak + 0][arow] = b4.x; Ks[ak + 1][arow] = b4.y;
        Ks[ak + 2][arow] = b4.z; Ks[ak + 3][arow] = b4.w;
        __syncthreads();
        const int ktn = (kt + 8 < S_) ? kt + 8 : kt;
        float4 a4n = *(const float4*)(Qp + ktn);
        float4 b4n = *(const float4*)(Kp + ktn);
        #pragma unroll
        for (int kk = 0; kk < 8; kk++) {
            float a[8], bb[8];
            *(float4*)&a[0]  = *(const float4*)&Qs[kk][ty * 8];
            *(float4*)&a[4]  = *(const float4*)&Qs[kk][ty * 8 + 4];
            *(float4*)&bb[0] = *(const float4*)&Ks[kk][tx * 8];
            *(float4*)&bb[4] = *(const float4*)&Ks[kk][tx * 8 + 4];
            #pragma unroll
            for (int i = 0; i < 8; i++)
                #pragma unroll
                for (int j = 0; j < 8; j++)
                    acc[i][j] += a[i] * bb[j];
        }
        __syncthreads();
        a4 = a4n; b4 = b4n;
    }

    const int row0 = bm * 128 + ty * 8;
    const int col0 = bn * 128 + tx * 8;
    u16* Ab = Aq + (size_t)b * N_ * 3072;
    #pragma unroll
    for (int i = 0; i < 8; i++) {
        u16* ar = Ab + (size_t)(row0 + i) * 3072;
        #pragma unroll
        for (int j = 0; j < 8; j++) {
            float t = acc[i][j] / 11.313708498984761f;
            t = fmaxf(t, 0.0f);
            t = t * t;
            u16 h = f2bf(t), l = f2bf(t - b2f(h));
            ar[col0 + j] = h; ar[1024 + col0 + j] = h; ar[2048 + col0 + j] = l;
        }
    }
}

// ---------------------------------------------------------------------------
// AV (MFMA): y = u .* (A@v); emits y' split-bf16 A-side [row][K'=3072]
// ---------------------------------------------------------------------------
__global__ __launch_bounds__(256) void av_mfma(
    const u16* __restrict__ Aq, const u16* __restrict__ vT,
    const float* __restrict__ u, u16* __restrict__ yP)
{
    __shared__ u16 As[128 * 32];
    __shared__ u16 Bs[128 * 32];
    f32x4 acc[4][4];
    #pragma unroll
    for (int i = 0; i < 4; i++)
        #pragma unroll
        for (int j = 0; j < 4; j++) acc[i][j] = (f32x4){0.f, 0.f, 0.f, 0.f};

    const int b = blockIdx.z;
    mm_tile_core(Aq + ((size_t)b * N_ + blockIdx.x * 128) * 3072,
                 vT + ((size_t)b * N_ + blockIdx.y * 128) * 3072, 3072,
                 As, Bs, acc);

    const int lane = threadIdx.x & 63, wid = threadIdx.x >> 6;
    const int wr = wid >> 1, wc = wid & 1;
    const int r0 = (lane >> 4) * 4, c0 = lane & 15;
    #pragma unroll
    for (int i = 0; i < 4; i++) {
        #pragma unroll
        for (int j = 0; j < 4; j++) {
            const int e = blockIdx.y * 128 + wc * 64 + j * 16 + c0;
            #pragma unroll
            for (int r = 0; r < 4; r++) {
                const int row = blockIdx.x * 128 + wr * 64 + i * 16 + r0 + r;
                const size_t gr = (size_t)b * N_ + row;
                float y = u[gr * E_ + e] * acc[i][j][r];
                u16 h = f2bf(y), l = f2bf(y - b2f(h));
                u16* yr = yP + gr * 3072;
                yr[e] = h; yr[1024 + e] = h; yr[2048 + e] = l;
            }
        }
    }
}

// ---------------------------------------------------------------------------
// Final (MFMA): out = y@Wo + bo + x
// ---------------------------------------------------------------------------
__global__ __launch_bounds__(256) void final_mfma(
    const u16* __restrict__ yP, const u16* __restrict__ WoT,
    const float* __restrict__ bo, const float* __restrict__ x,
    float* __restrict__ out)
{
    __shared__ u16 As[128 * 32];
    __shared__ u16 Bs[128 * 32];
    f32x4 acc[4][4];
    #pragma unroll
    for (int i = 0; i < 4; i++)
        #pragma unroll
        for (int j = 0; j < 4; j++) acc[i][j] = (f32x4){0.f, 0.f, 0.f, 0.f};

    mm_tile_core(yP + (size_t)blockIdx.x * 128 * 3072,
                 WoT + (size_t)blockIdx.y * 128 * 3072, 3072, As, Bs, acc);

    const int lane = threadIdx.x & 63, wid = threadIdx.x >> 6;
    const int wr = wid >> 1, wc = wid & 1;
    const int r0 = (lane >> 4) * 4, c0 = lane & 15;
    #pragma unroll
    for (int i = 0; i < 4; i++) {
        #pragma unroll
        for (int j = 0; j < 4; j++) {
            const int col = blockIdx.y * 128 + wc * 64 + j * 16 + c0;
            const float bc = bo[col];
            #pragma unroll
            for (int r = 0; r < 4; r++) {
                const int row = blockIdx.x * 128 + wr * 64 + i * 16 + r0 + r;
                out[(size_t)row * H_ + col] =
                    acc[i][j][r] + bc + x[(size_t)row * H_ + col];
            }
        }
    }
}

// ---------------------------------------------------------------------------
extern "C" void kernel_launch(void* const* d_in, const int* in_sizes, int n_in,
                              void* d_out, int out_size, void* d_ws, size_t ws_size,
                              hipStream_t stream)
{
    const float* x     = (const float*)d_in[0];
    const float* Wuv   = (const float*)d_in[1];
    const float* buv   = (const float*)d_in[2];
    const float* gamma = (const float*)d_in[3];
    const float* beta  = (const float*)d_in[4];
    const float* Wo    = (const float*)d_in[5];
    const float* bo    = (const float*)d_in[6];
    const float* g     = (const float*)d_in[7];
    float* out = (float*)d_out;

    // --- ws carve, ws_size-adaptive chunking -------------------------------
    const size_t fixedB = (size_t)R_ * 4 + 2 * 65536 * 4          // s + trig
                        + (size_t)NW_ * 1536 * 2                  // WuvT'
                        + (size_t)H_ * 3072 * 2;                  // WoT'
    const size_t perBatchB = 27262976ull;  // xn'+qb+kb+u+vT'+A'+y' per batch
    int c = 8;                             // cap: need(8) ~= 229 MB
    while (c > 1) {
        if (fixedB + (size_t)c * perBatchB <= ws_size) break;
        c >>= 1;
    }
    const int Rc = c * N_;

    char* p = (char*)d_ws;
    float* s_buf = (float*)p;  p += (size_t)R_ * 4;
    float* sin_t = (float*)p;  p += (size_t)N_ * 64 * 4;
    float* cos_t = (float*)p;  p += (size_t)N_ * 64 * 4;
    u16*   WuvT  = (u16*)p;    p += (size_t)NW_ * 1536 * 2;
    u16*   WoT   = (u16*)p;    p += (size_t)H_ * 3072 * 2;
    u16*   xnP   = (u16*)p;    p += (size_t)Rc * 1536 * 2;
    float* qb    = (float*)p;  p += (size_t)Rc * S_ * 4;
    float* kb    = (float*)p;  p += (size_t)Rc * S_ * 4;
    float* u_c   = (float*)p;  p += (size_t)Rc * E_ * 4;
    u16*   vT    = (u16*)p;    p += (size_t)Rc * 3072 * 2;
    u16*   Aq    = (u16*)p;    p += (size_t)Rc * 3072 * 2;
    u16*   yP    = (u16*)p;    p += (size_t)Rc * 3072 * 2;

    scale_kernel<<<R_ / 4, 256, 0, stream>>>(x, g, s_buf);
    trig_kernel<<<(N_ * 64) / 256, 256, 0, stream>>>(sin_t, cos_t);
    wuvt_kernel<<<H_, 256, 0, stream>>>(Wuv, WuvT);
    wot_kernel<<<E_, 256, 0, stream>>>(Wo, WoT);

    for (int b0 = 0; b0 < B_; b0 += c) {
        const size_t ro = (size_t)b0 * N_;
        xnp_kernel<<<(Rc * 512) / 256, 256, 0, stream>>>(
            x + ro * H_, s_buf + ro, xnP);
        gemm1_mfma<<<dim3(Rc / 128, NW_ / 128), 256, 0, stream>>>(
            xnP, WuvT, buv, u_c, vT, qb);
        rope_kernel<<<Rc / 4, 256, 0, stream>>>(
            qb, kb, gamma, beta, sin_t, cos_t);
        qk_kernel<<<dim3(N_ / 128, N_ / 128, c), 256, 0, stream>>>(
            qb, kb, Aq);
        av_mfma<<<dim3(N_ / 128, N_ / 128, c), 256, 0, stream>>>(
            Aq, vT, u_c, yP);
        final_mfma<<<dim3(Rc / 128, H_ / 128), 256, 0, stream>>>(
            yP, WoT, bo, x + ro * H_, out + ro * H_);
    }
}